// Round 15
// baseline (313.999 us; speedup 1.0000x reference)
//
#include <hip/hip_runtime.h>
#include <hip/hip_bf16.h>
#include <hip/hip_fp16.h>
#include <math.h>

// Problem constants
#define NN 100000
#define EE 1600000
#define ET 1700000            // E + N self-loops
#define NEG_SLOPE 0.2f
#define XS_STRIDE 136         // 128 + 8 halves: kills LDS bank conflicts

// bucket-sort CSR build (fixed slabs; no count/scan passes)
#define BKB 8                 // log2(dsts per bucket)
#define BKSZ 256
#define NBUCK 391             // ceil(NN / BKSZ)
#define SLAB 8192             // slots per bucket (mean ~4350, 58 sigma safe)
#define PAD 32                // ints per counter (one 128B line each)
#define EPT2 16
#define CHUNK2 (256 * EPT2)   // 4096 edges per block
#define NCH2 ((ET + CHUNK2 - 1) / CHUNK2)   // 416

typedef _Float16 f16;
typedef f16 f16x8 __attribute__((ext_vector_type(8)));
typedef float f32x4 __attribute__((ext_vector_type(4)));

__device__ __forceinline__ float leaky(float v) {
    return v > 0.f ? v : NEG_SLOPE * v;
}
__device__ __forceinline__ unsigned char enc_fp8(float v) {
    int pk = __builtin_amdgcn_cvt_pk_fp8_f32(v, 0.f, 0, false);
    return (unsigned char)(pk & 0xff);
}

// ---------- W1 fp32 [128][64] -> wt fp16 [64][128] (transposed) ----------
__global__ __launch_bounds__(256) void convert_w_kernel(
        const float* __restrict__ W1, f16* __restrict__ wt) {
    int i = blockIdx.x * 256 + threadIdx.x;
    if (i < 128 * 64) {
        int n = i >> 7, k = i & 127;
        wt[n * 128 + k] = (f16)W1[k * 64 + n];
    }
}

// ---------- GEMM1 via MFMA; fused alpha epilogue ----------
// Writes h1f8 (fp8, for conv1 gather) + as1h/ad1 logits. No fp16 h1 array.
__global__ __launch_bounds__(256) void gemm1_mfma(
        const float* __restrict__ x, const f16* __restrict__ wt,
        const float* __restrict__ att_s, const float* __restrict__ att_d,
        unsigned char* __restrict__ h1f8, __half* __restrict__ as1h,
        float* __restrict__ ad1o) {
    __shared__ f16 xs[64 * XS_STRIDE];
    const int tid = threadIdx.x;
    const int node0 = blockIdx.x * 64;
    for (int i = tid; i < 64 * 64; i += 256) {
        int r = i >> 6, cp = i & 63;
        int n = node0 + r;
        float2 v = (n < NN) ? ((const float2*)x)[(long)n * 64 + cp]
                            : make_float2(0.f, 0.f);
        xs[r * XS_STRIDE + 2 * cp]     = (f16)v.x;
        xs[r * XS_STRIDE + 2 * cp + 1] = (f16)v.y;
    }
    __syncthreads();
    const int wv = tid >> 6;
    const int lane = tid & 63;
    const int n16 = lane & 15;
    const int quad = lane >> 4;
    f16x8 bf[4][4];
#pragma unroll
    for (int t = 0; t < 4; ++t)
#pragma unroll
        for (int kk = 0; kk < 4; ++kk)
            bf[t][kk] = *(const f16x8*)(wt + ((t * 16 + n16) * 128 + kk * 32 + quad * 8));
    f32x4 acc[4] = {{0,0,0,0},{0,0,0,0},{0,0,0,0},{0,0,0,0}};
#pragma unroll
    for (int kk = 0; kk < 4; ++kk) {
        f16x8 af = *(const f16x8*)(xs + ((wv * 16 + n16) * XS_STRIDE + kk * 32 + quad * 8));
#pragma unroll
        for (int t = 0; t < 4; ++t)
            acc[t] = __builtin_amdgcn_mfma_f32_16x16x32_f16(af, bf[t][kk], acc[t], 0, 0, 0);
    }
    float ats[4], atd[4];
#pragma unroll
    for (int t = 0; t < 4; ++t) {
        ats[t] = att_s[t * 16 + n16];
        atd[t] = att_d[t * 16 + n16];
    }
#pragma unroll
    for (int t = 0; t < 4; ++t)
#pragma unroll
        for (int r = 0; r < 4; ++r) {
            int m = node0 + wv * 16 + quad * 4 + r;
            bool ok = (m < NN);
            if (ok) h1f8[m * 64 + t * 16 + n16] = enc_fp8(acc[t][r]);
            float vs = acc[t][r] * ats[t];
            float vd = acc[t][r] * atd[t];
            vs += __shfl_xor(vs, 1, 64); vd += __shfl_xor(vd, 1, 64);
            vs += __shfl_xor(vs, 2, 64); vd += __shfl_xor(vd, 2, 64);
            vs += __shfl_xor(vs, 4, 64); vd += __shfl_xor(vd, 4, 64);
            if (ok && (n16 & 7) == 0) {
                int h = t * 2 + (n16 >> 3);
                as1h[m * 8 + h] = __float2half_rn(vs);
                ad1o[m * 8 + h] = vd;
            }
        }
}

// ---------- B1: bucket fill into fixed slabs — payload rel<<17|src -------
__global__ __launch_bounds__(256) void bucket_fill(
        const int* __restrict__ ei, int* __restrict__ bcur,
        unsigned* __restrict__ gpay) {
    __shared__ int lcnt[NBUCK];
    __shared__ int gbase[NBUCK];
    const int tid = threadIdx.x;
    for (int i = tid; i < NBUCK; i += 256) lcnt[i] = 0;
    __syncthreads();
    const int base = blockIdx.x * CHUNK2 + tid;
    unsigned pay[EPT2];
    int bk[EPT2], pos[EPT2];
#pragma unroll
    for (int k = 0; k < EPT2; ++k) {
        int e = base + k * 256;
        if (e < ET) {
            int s, d;
            if (e < EE) {
                s = __builtin_nontemporal_load(ei + e);
                d = __builtin_nontemporal_load(ei + EE + e);
            } else { s = d = e - EE; }
            int b = d >> BKB;
            bk[k] = b;
            pay[k] = ((unsigned)(d & (BKSZ - 1)) << 17) | (unsigned)s;
            pos[k] = atomicAdd(&lcnt[b], 1);
        } else bk[k] = -1;
    }
    __syncthreads();
    for (int i = tid; i < NBUCK; i += 256)
        gbase[i] = lcnt[i] ? (i * SLAB + atomicAdd(&bcur[i * PAD], lcnt[i])) : 0;
    __syncthreads();
#pragma unroll
    for (int k = 0; k < EPT2; ++k)
        if (bk[k] >= 0) gpay[gbase[bk[k]] + pos[k]] = pay[k];
}

// ---------- B2: fine CSR within each bucket slab ----------
__global__ __launch_bounds__(256) void fine_csr(
        const unsigned* __restrict__ gpay, const int* __restrict__ bcur,
        int* __restrict__ rowptr, int* __restrict__ rowend,
        int* __restrict__ csr_src) {
    __shared__ int cnt[BKSZ];     // 256: hist -> cursors
    __shared__ int ts[256];
    const int b = blockIdx.x;
    const int tid = threadIdx.x;
    const int off = b * SLAB;
    int blen = bcur[b * PAD];
    if (blen > SLAB) blen = SLAB;
    const int d0 = b << BKB;
    cnt[tid] = 0;
    __syncthreads();
    for (int i = tid; i < blen; i += 256)
        atomicAdd(&cnt[gpay[off + i] >> 17], 1);
    __syncthreads();
    int v = cnt[tid];
    ts[tid] = v;
    __syncthreads();
    for (int o = 1; o < 256; o <<= 1) {
        int u = (tid >= o) ? ts[tid - o] : 0;
        __syncthreads();
        ts[tid] += u;
        __syncthreads();
    }
    int excl = ts[tid] - v;
    cnt[tid] = excl;              // cursor = exclusive offset
    int d = d0 + tid;
    if (d < NN) {
        rowptr[d] = off + excl;
        rowend[d] = off + excl + v;
    }
    __syncthreads();
    for (int i = tid; i < blen; i += 256) {
        unsigned pay = gpay[off + i];
        int pos = atomicAdd(&cnt[pay >> 17], 1);
        csr_src[off + pos] = (int)(pay & 0x1FFFFu);
    }
}

// ---------- conv1 fused: 2 waves per node, lane-split weights + fp8 gather
// Block = 4 waves = 2 nodes; wave (slot, half) does half the edge range,
// LDS-combines (l, acc); half==0 wave runs the gemm2 epilogue.
__global__ __launch_bounds__(256) void conv1_fused_kernel(
        const int* __restrict__ rowptr, const int* __restrict__ rowend,
        const int* __restrict__ csr_src, const __half* __restrict__ as1h,
        const float* __restrict__ ad1,
        const unsigned char* __restrict__ h1f8, const float* __restrict__ b1,
        const float* __restrict__ W2, const float* __restrict__ as2,
        const float* __restrict__ ad2, float4* __restrict__ rec) {
    __shared__ float lsum[4 * 64];
    __shared__ float lacc[4 * 64];
    const int tid = threadIdx.x;
    const int wv = tid >> 6;         // 0..3
    const int c = tid & 63;
    const int slot = wv >> 1;        // node slot in block
    const int half = wv & 1;
    int n = blockIdx.x * 2 + slot;   // grid = NN/2 blocks; always < NN
    n = __builtin_amdgcn_readfirstlane(n);
    int h = c >> 3;                  // accumulation head
    int kB = c >> 3;                 // edge slot this lane weighs
    int hB = c & 7;                  // head this lane weighs
    float adh = ad1[n * 8 + h];
    float adB = ad1[n * 8 + hB];
    const int bperm_base = h << 2;
    int jb0 = rowptr[n], je0 = rowend[n];
    int mid = jb0 + ((je0 - jb0 + 1) >> 1);
    int jb = half ? mid : jb0;
    int je = half ? je0 : mid;
    float l0 = 0.f, l1 = 0.f, l2 = 0.f, l3 = 0.f;
    float a0 = 0.f, a1 = 0.f, a2 = 0.f, a3 = 0.f;
    int j = jb;
    for (; j + 7 < je; j += 8) {
        int myS = csr_src[j + kB];
        float myp = __expf(leaky(__half2float(as1h[myS * 8 + hB]) + adB));
        int mypi = __float_as_int(myp);
#pragma unroll
        for (int k = 0; k < 8; ++k) {
            int sk = csr_src[j + k];
            float pk = __int_as_float(
                __builtin_amdgcn_ds_bpermute(bperm_base + (k << 5), mypi));
            float fk = __builtin_amdgcn_cvt_f32_fp8((int)h1f8[sk * 64 + c], 0);
            switch (k & 3) {
                case 0: l0 += pk; a0 += pk * fk; break;
                case 1: l1 += pk; a1 += pk * fk; break;
                case 2: l2 += pk; a2 += pk * fk; break;
                default: l3 += pk; a3 += pk * fk; break;
            }
        }
    }
    for (; j < je; ++j) {
        int s = csr_src[j];
        float p = __expf(leaky(__half2float(as1h[s * 8 + h]) + adh));
        float f = __builtin_amdgcn_cvt_f32_fp8((int)h1f8[s * 64 + c], 0);
        l0 += p;
        a0 += p * f;
    }
    float l = (l0 + l1) + (l2 + l3);
    float acc = (a0 + a1) + (a2 + a3);
    lsum[wv * 64 + c] = l;
    lacc[wv * 64 + c] = acc;
    __syncthreads();
    if (half) return;
    l   += lsum[(wv + 1) * 64 + c];
    acc += lacc[(wv + 1) * 64 + c];
    float o = acc / (l + 1e-16f);
    float a = o + b1[c];
    a = a > 0.f ? a : 0.f;                 // ReLU
    float r0 = a * W2[c * 2];
    float r1 = a * W2[c * 2 + 1];
#pragma unroll
    for (int off = 32; off > 0; off >>= 1) {
        r0 += __shfl_xor(r0, off, 64);
        r1 += __shfl_xor(r1, off, 64);
    }
    if (c == 0) {
        float s2v = r0 * as2[0] + r1 * as2[1];
        float d2v = r0 * ad2[0] + r1 * ad2[1];
        rec[n] = make_float4(s2v, r0, r1, d2v);   // (as2o, h2_0, h2_1, ad2o)
    }
}

// ---------- conv2 fused with mean-pool (LDS partials, 4-way ILP) ----------
__global__ __launch_bounds__(256) void conv2_pool_kernel(
        const int* __restrict__ rowptr, const int* __restrict__ rowend,
        const int* __restrict__ csr_src, const float4* __restrict__ rec,
        const int* __restrict__ batch,
        float* __restrict__ pooled /*128 sums + 64 counts*/) {
    __shared__ float ls[192];
    int tid = threadIdx.x;
    if (tid < 192) ls[tid] = 0.f;
    __syncthreads();
    int n = blockIdx.x * 256 + tid;
    if (n < NN) {
        float adn = rec[n].w;
        int jb = rowptr[n], je = rowend[n];
        float l0 = 0.f, l1 = 0.f, l2 = 0.f, l3 = 0.f;
        float x0 = 0.f, x1 = 0.f, x2 = 0.f, x3 = 0.f;
        float y0 = 0.f, y1 = 0.f, y2 = 0.f, y3 = 0.f;
        int j = jb;
        for (; j + 3 < je; j += 4) {
            float4 ra = rec[csr_src[j]];
            float4 rb = rec[csr_src[j + 1]];
            float4 rc = rec[csr_src[j + 2]];
            float4 rd = rec[csr_src[j + 3]];
            float pa = __expf(leaky(ra.x + adn));
            float pb = __expf(leaky(rb.x + adn));
            float pc = __expf(leaky(rc.x + adn));
            float pd = __expf(leaky(rd.x + adn));
            l0 += pa; x0 += pa * ra.y; y0 += pa * ra.z;
            l1 += pb; x1 += pb * rb.y; y1 += pb * rb.z;
            l2 += pc; x2 += pc * rc.y; y2 += pc * rc.z;
            l3 += pd; x3 += pd * rd.y; y3 += pd * rd.z;
        }
        for (; j < je; ++j) {
            float4 ra = rec[csr_src[j]];
            float pa = __expf(leaky(ra.x + adn));
            l0 += pa; x0 += pa * ra.y; y0 += pa * ra.z;
        }
        float l = (l0 + l1) + (l2 + l3);
        float xx = (x0 + x1) + (x2 + x3);
        float yy = (y0 + y1) + (y2 + y3);
        float inv = 1.f / (l + 1e-16f);
        int g = batch[n];
        atomicAdd(&ls[g * 2],     xx * inv);
        atomicAdd(&ls[g * 2 + 1], yy * inv);
        atomicAdd(&ls[128 + g],   1.f);
    }
    __syncthreads();
    if (tid < 192) atomicAdd(&pooled[tid], ls[tid]);
}

// ---------- finalize: mean, +b2, log_softmax ----------
__global__ __launch_bounds__(64) void final_kernel(
        const float* __restrict__ pooled, const float* __restrict__ b2,
        float* __restrict__ out) {
    int g = threadIdx.x;
    if (g >= 64) return;
    float c = pooled[128 + g];
    float denom = c > 1.f ? c : 1.f;
    float p0 = pooled[g * 2] / denom + b2[0];
    float p1 = pooled[g * 2 + 1] / denom + b2[1];
    float m = fmaxf(p0, p1);
    float lse = m + logf(expf(p0 - m) + expf(p1 - m));
    out[g * 2] = p0 - lse;
    out[g * 2 + 1] = p1 - lse;
}

extern "C" void kernel_launch(void* const* d_in, const int* in_sizes, int n_in,
                              void* d_out, int out_size, void* d_ws, size_t ws_size,
                              hipStream_t stream) {
    const float* x   = (const float*)d_in[0];
    const int*   ei  = (const int*)d_in[1];     // [2,E] int32
    const int*   bat = (const int*)d_in[2];     // [N]
    const float* W1  = (const float*)d_in[3];
    const float* as1 = (const float*)d_in[4];
    const float* ad1 = (const float*)d_in[5];
    const float* b1  = (const float*)d_in[6];
    const float* W2  = (const float*)d_in[7];
    const float* as2 = (const float*)d_in[8];
    const float* ad2 = (const float*)d_in[9];
    const float* b2  = (const float*)d_in[10];
    float* out = (float*)d_out;

    float* ws = (float*)d_ws;
    // workspace layout (element offsets; 16B-aligned blocks)
    const long off_h1f8   = 0;                          // N*64 bytes = N*16 f
    const long off_wt     = off_h1f8 + (long)NN * 16;   // 8192 halves = 4096 f
    const long off_as1h   = off_wt   + 4096;            // N*8 halves = N*4 f
    const long off_ad1    = off_as1h + (long)NN * 4;    // N*8
    const long off_rec    = off_ad1  + (long)NN * 8;    // N*4 (float4)
    const long off_rowptr = off_rec  + (long)NN * 4;    // N (int)
    const long off_rowend = off_rowptr + NN;            // N (int)
    const long off_gpay   = off_rowend + NN;            // NBUCK*SLAB (uint)
    const long off_csr    = off_gpay + (long)NBUCK * SLAB; // NBUCK*SLAB (int)
    const long off_zero   = off_csr  + (long)NBUCK * SLAB; // ---- zeroed ----
    const long off_bcur   = off_zero;                   // NBUCK*PAD (int)
    const long off_pool   = off_bcur + NBUCK * PAD;     // 192
    const long zero_elems = off_pool + 192 - off_zero;

    hipMemsetAsync(ws + off_zero, 0, zero_elems * sizeof(float), stream);

    convert_w_kernel<<<32, 256, 0, stream>>>(W1, (f16*)(ws + off_wt));
    gemm1_mfma<<<(NN + 63) / 64, 256, 0, stream>>>(
        x, (const f16*)(ws + off_wt), as1, ad1,
        (unsigned char*)(ws + off_h1f8), (__half*)(ws + off_as1h),
        ws + off_ad1);

    bucket_fill<<<NCH2, 256, 0, stream>>>(ei, (int*)(ws + off_bcur),
                                          (unsigned*)(ws + off_gpay));
    fine_csr<<<NBUCK, 256, 0, stream>>>(
        (const unsigned*)(ws + off_gpay), (const int*)(ws + off_bcur),
        (int*)(ws + off_rowptr), (int*)(ws + off_rowend),
        (int*)(ws + off_csr));

    conv1_fused_kernel<<<NN / 2, 256, 0, stream>>>(
        (const int*)(ws + off_rowptr), (const int*)(ws + off_rowend),
        (const int*)(ws + off_csr), (const __half*)(ws + off_as1h),
        ws + off_ad1, (const unsigned char*)(ws + off_h1f8),
        b1, W2, as2, ad2, (float4*)(ws + off_rec));

    conv2_pool_kernel<<<(NN + 255) / 256, 256, 0, stream>>>(
        (const int*)(ws + off_rowptr), (const int*)(ws + off_rowend),
        (const int*)(ws + off_csr), (const float4*)(ws + off_rec),
        bat, ws + off_pool);

    final_kernel<<<1, 64, 0, stream>>>(ws + off_pool, b2, out);
}

// Round 16
// 249.567 us; speedup vs baseline: 1.2582x; 1.2582x over previous
//
#include <hip/hip_runtime.h>
#include <hip/hip_bf16.h>
#include <hip/hip_fp16.h>
#include <math.h>

// Problem constants
#define NN 100000
#define EE 1600000
#define ET 1700000            // E + N self-loops
#define NEG_SLOPE 0.2f
#define XS_STRIDE 136         // 128 + 8 halves: kills LDS bank conflicts

// bucket-sort CSR build (fixed slabs; no count/scan passes)
#define BKB 8                 // log2(dsts per bucket)
#define BKSZ 256
#define NBUCK 391             // ceil(NN / BKSZ)
#define SLAB 8192             // slots per bucket (mean ~4350, 58 sigma safe)
#define PAD 32                // ints per counter (one 128B line each)
#define EPT2 16
#define CHUNK2 (256 * EPT2)   // 4096 edges per block
#define NCH2 ((ET + CHUNK2 - 1) / CHUNK2)   // 416

typedef _Float16 f16;
typedef f16 f16x8 __attribute__((ext_vector_type(8)));
typedef float f32x4 __attribute__((ext_vector_type(4)));

__device__ __forceinline__ float leaky(float v) {
    return v > 0.f ? v : NEG_SLOPE * v;
}
__device__ __forceinline__ unsigned char enc_fp8(float v) {
    int pk = __builtin_amdgcn_cvt_pk_fp8_f32(v, 0.f, 0, false);
    return (unsigned char)(pk & 0xff);
}

// ---------- W1 fp32 [128][64] -> wt fp16 [64][128] (transposed) ----------
__global__ __launch_bounds__(256) void convert_w_kernel(
        const float* __restrict__ W1, f16* __restrict__ wt) {
    int i = blockIdx.x * 256 + threadIdx.x;
    if (i < 128 * 64) {
        int n = i >> 7, k = i & 127;
        wt[n * 128 + k] = (f16)W1[k * 64 + n];
    }
}

// ---------- GEMM1 via MFMA; fused alpha epilogue ----------
__global__ __launch_bounds__(256) void gemm1_mfma(
        const float* __restrict__ x, const f16* __restrict__ wt,
        const float* __restrict__ att_s, const float* __restrict__ att_d,
        unsigned char* __restrict__ h1f8, __half* __restrict__ as1h,
        float* __restrict__ ad1o) {
    __shared__ f16 xs[64 * XS_STRIDE];
    const int tid = threadIdx.x;
    const int node0 = blockIdx.x * 64;
    for (int i = tid; i < 64 * 64; i += 256) {
        int r = i >> 6, cp = i & 63;
        int n = node0 + r;
        float2 v = (n < NN) ? ((const float2*)x)[(long)n * 64 + cp]
                            : make_float2(0.f, 0.f);
        xs[r * XS_STRIDE + 2 * cp]     = (f16)v.x;
        xs[r * XS_STRIDE + 2 * cp + 1] = (f16)v.y;
    }
    __syncthreads();
    const int wv = tid >> 6;
    const int lane = tid & 63;
    const int n16 = lane & 15;
    const int quad = lane >> 4;
    f16x8 bf[4][4];
#pragma unroll
    for (int t = 0; t < 4; ++t)
#pragma unroll
        for (int kk = 0; kk < 4; ++kk)
            bf[t][kk] = *(const f16x8*)(wt + ((t * 16 + n16) * 128 + kk * 32 + quad * 8));
    f32x4 acc[4] = {{0,0,0,0},{0,0,0,0},{0,0,0,0},{0,0,0,0}};
#pragma unroll
    for (int kk = 0; kk < 4; ++kk) {
        f16x8 af = *(const f16x8*)(xs + ((wv * 16 + n16) * XS_STRIDE + kk * 32 + quad * 8));
#pragma unroll
        for (int t = 0; t < 4; ++t)
            acc[t] = __builtin_amdgcn_mfma_f32_16x16x32_f16(af, bf[t][kk], acc[t], 0, 0, 0);
    }
    float ats[4], atd[4];
#pragma unroll
    for (int t = 0; t < 4; ++t) {
        ats[t] = att_s[t * 16 + n16];
        atd[t] = att_d[t * 16 + n16];
    }
#pragma unroll
    for (int t = 0; t < 4; ++t)
#pragma unroll
        for (int r = 0; r < 4; ++r) {
            int m = node0 + wv * 16 + quad * 4 + r;
            bool ok = (m < NN);
            if (ok) h1f8[m * 64 + t * 16 + n16] = enc_fp8(acc[t][r]);
            float vs = acc[t][r] * ats[t];
            float vd = acc[t][r] * atd[t];
            vs += __shfl_xor(vs, 1, 64); vd += __shfl_xor(vd, 1, 64);
            vs += __shfl_xor(vs, 2, 64); vd += __shfl_xor(vd, 2, 64);
            vs += __shfl_xor(vs, 4, 64); vd += __shfl_xor(vd, 4, 64);
            if (ok && (n16 & 7) == 0) {
                int h = t * 2 + (n16 >> 3);
                as1h[m * 8 + h] = __float2half_rn(vs);
                ad1o[m * 8 + h] = vd;
            }
        }
}

// ---------- B1: bucket fill into fixed slabs — payload rel<<17|src -------
__global__ __launch_bounds__(256) void bucket_fill(
        const int* __restrict__ ei, int* __restrict__ bcur,
        unsigned* __restrict__ gpay) {
    __shared__ int lcnt[NBUCK];
    __shared__ int gbase[NBUCK];
    const int tid = threadIdx.x;
    for (int i = tid; i < NBUCK; i += 256) lcnt[i] = 0;
    __syncthreads();
    const int base = blockIdx.x * CHUNK2 + tid;
    unsigned pay[EPT2];
    int bk[EPT2], pos[EPT2];
#pragma unroll
    for (int k = 0; k < EPT2; ++k) {
        int e = base + k * 256;
        if (e < ET) {
            int s, d;
            if (e < EE) {
                s = __builtin_nontemporal_load(ei + e);
                d = __builtin_nontemporal_load(ei + EE + e);
            } else { s = d = e - EE; }
            int b = d >> BKB;
            bk[k] = b;
            pay[k] = ((unsigned)(d & (BKSZ - 1)) << 17) | (unsigned)s;
            pos[k] = atomicAdd(&lcnt[b], 1);
        } else bk[k] = -1;
    }
    __syncthreads();
    for (int i = tid; i < NBUCK; i += 256)
        gbase[i] = lcnt[i] ? (i * SLAB + atomicAdd(&bcur[i * PAD], lcnt[i])) : 0;
    __syncthreads();
#pragma unroll
    for (int k = 0; k < EPT2; ++k)
        if (bk[k] >= 0) gpay[gbase[bk[k]] + pos[k]] = pay[k];
}

// ---------- B2: fine CSR within each bucket slab ----------
__global__ __launch_bounds__(256) void fine_csr(
        const unsigned* __restrict__ gpay, const int* __restrict__ bcur,
        int* __restrict__ rowptr, int* __restrict__ rowend,
        int* __restrict__ csr_src) {
    __shared__ int cnt[BKSZ];     // 256: hist -> cursors
    __shared__ int ts[256];
    const int b = blockIdx.x;
    const int tid = threadIdx.x;
    const int off = b * SLAB;
    int blen = bcur[b * PAD];
    if (blen > SLAB) blen = SLAB;
    const int d0 = b << BKB;
    cnt[tid] = 0;
    __syncthreads();
    for (int i = tid; i < blen; i += 256)
        atomicAdd(&cnt[gpay[off + i] >> 17], 1);
    __syncthreads();
    int v = cnt[tid];
    ts[tid] = v;
    __syncthreads();
    for (int o = 1; o < 256; o <<= 1) {
        int u = (tid >= o) ? ts[tid - o] : 0;
        __syncthreads();
        ts[tid] += u;
        __syncthreads();
    }
    int excl = ts[tid] - v;
    cnt[tid] = excl;              // cursor = exclusive offset
    int d = d0 + tid;
    if (d < NN) {
        rowptr[d] = off + excl;
        rowend[d] = off + excl + v;
    }
    __syncthreads();
    for (int i = tid; i < blen; i += 256) {
        unsigned pay = gpay[off + i];
        int pos = atomicAdd(&cnt[pay >> 17], 1);
        csr_src[off + pos] = (int)(pay & 0x1FFFFu);
    }
}

// ---------- conv1 fused: 2 nodes per wave (interleaved chains) ------------
// Full-length ranges keep the 8-edge lane-split fast path dominant; the two
// independent chains double memory-level parallelism per wave.
__global__ __launch_bounds__(256) void conv1_fused_kernel(
        const int* __restrict__ rowptr, const int* __restrict__ rowend,
        const int* __restrict__ csr_src, const __half* __restrict__ as1h,
        const float* __restrict__ ad1,
        const unsigned char* __restrict__ h1f8, const float* __restrict__ b1,
        const float* __restrict__ W2, const float* __restrict__ as2,
        const float* __restrict__ ad2, float4* __restrict__ rec) {
    const int tid = threadIdx.x;
    const int wv = tid >> 6;
    const int c = tid & 63;
    int n0 = __builtin_amdgcn_readfirstlane((blockIdx.x * 4 + wv) * 2);
    int n1 = n0 + 1;                 // grid*4*2 == NN exactly
    int h = c >> 3;                  // accumulation head
    int kB = c >> 3;                 // edge slot this lane weighs
    int hB = c & 7;                  // head this lane weighs
    float adA = ad1[n0 * 8 + hB], adB = ad1[n1 * 8 + hB];
    float adhA = ad1[n0 * 8 + h],  adhB = ad1[n1 * 8 + h];
    const int bperm_base = h << 2;
    int jA = rowptr[n0], eA = rowend[n0];
    int jB = rowptr[n1], eB = rowend[n1];
    float lA0 = 0.f, lA1 = 0.f, aA0 = 0.f, aA1 = 0.f;
    float lB0 = 0.f, lB1 = 0.f, aB0 = 0.f, aB1 = 0.f;
    // interleaved main: 8 edges of A + 8 edges of B per iteration
    while (jA + 7 < eA && jB + 7 < eB) {
        int mySA = csr_src[jA + kB];
        int mySB = csr_src[jB + kB];
        float pA = __expf(leaky(__half2float(as1h[mySA * 8 + hB]) + adA));
        float pB = __expf(leaky(__half2float(as1h[mySB * 8 + hB]) + adB));
        int piA = __float_as_int(pA), piB = __float_as_int(pB);
#pragma unroll
        for (int k = 0; k < 8; ++k) {
            int skA = csr_src[jA + k];
            int skB = csr_src[jB + k];
            float pkA = __int_as_float(
                __builtin_amdgcn_ds_bpermute(bperm_base + (k << 5), piA));
            float pkB = __int_as_float(
                __builtin_amdgcn_ds_bpermute(bperm_base + (k << 5), piB));
            float fkA = __builtin_amdgcn_cvt_f32_fp8((int)h1f8[skA * 64 + c], 0);
            float fkB = __builtin_amdgcn_cvt_f32_fp8((int)h1f8[skB * 64 + c], 0);
            if (k & 1) { lA1 += pkA; aA1 += pkA * fkA; lB1 += pkB; aB1 += pkB * fkB; }
            else       { lA0 += pkA; aA0 += pkA * fkA; lB0 += pkB; aB0 += pkB * fkB; }
        }
        jA += 8; jB += 8;
    }
    // finish A
    for (; jA + 7 < eA; jA += 8) {
        int myS = csr_src[jA + kB];
        float myp = __expf(leaky(__half2float(as1h[myS * 8 + hB]) + adA));
        int mypi = __float_as_int(myp);
#pragma unroll
        for (int k = 0; k < 8; ++k) {
            int sk = csr_src[jA + k];
            float pk = __int_as_float(
                __builtin_amdgcn_ds_bpermute(bperm_base + (k << 5), mypi));
            float fk = __builtin_amdgcn_cvt_f32_fp8((int)h1f8[sk * 64 + c], 0);
            if (k & 1) { lA1 += pk; aA1 += pk * fk; }
            else       { lA0 += pk; aA0 += pk * fk; }
        }
    }
    for (; jA < eA; ++jA) {
        int s = csr_src[jA];
        float p = __expf(leaky(__half2float(as1h[s * 8 + h]) + adhA));
        float f = __builtin_amdgcn_cvt_f32_fp8((int)h1f8[s * 64 + c], 0);
        lA0 += p; aA0 += p * f;
    }
    // finish B
    for (; jB + 7 < eB; jB += 8) {
        int myS = csr_src[jB + kB];
        float myp = __expf(leaky(__half2float(as1h[myS * 8 + hB]) + adB));
        int mypi = __float_as_int(myp);
#pragma unroll
        for (int k = 0; k < 8; ++k) {
            int sk = csr_src[jB + k];
            float pk = __int_as_float(
                __builtin_amdgcn_ds_bpermute(bperm_base + (k << 5), mypi));
            float fk = __builtin_amdgcn_cvt_f32_fp8((int)h1f8[sk * 64 + c], 0);
            if (k & 1) { lB1 += pk; aB1 += pk * fk; }
            else       { lB0 += pk; aB0 += pk * fk; }
        }
    }
    for (; jB < eB; ++jB) {
        int s = csr_src[jB];
        float p = __expf(leaky(__half2float(as1h[s * 8 + h]) + adhB));
        float f = __builtin_amdgcn_cvt_f32_fp8((int)h1f8[s * 64 + c], 0);
        lB0 += p; aB0 += p * f;
    }
    // epilogue, node A then node B
    float lA = lA0 + lA1, accA = aA0 + aA1;
    float lB = lB0 + lB1, accB = aB0 + aB1;
    float aAv = accA / (lA + 1e-16f) + b1[c];
    float aBv = accB / (lB + 1e-16f) + b1[c];
    aAv = aAv > 0.f ? aAv : 0.f;
    aBv = aBv > 0.f ? aBv : 0.f;
    float w20 = W2[c * 2], w21 = W2[c * 2 + 1];
    float rA0 = aAv * w20, rA1 = aAv * w21;
    float rB0 = aBv * w20, rB1 = aBv * w21;
#pragma unroll
    for (int off = 32; off > 0; off >>= 1) {
        rA0 += __shfl_xor(rA0, off, 64);
        rA1 += __shfl_xor(rA1, off, 64);
        rB0 += __shfl_xor(rB0, off, 64);
        rB1 += __shfl_xor(rB1, off, 64);
    }
    if (c == 0) {
        rec[n0] = make_float4(rA0 * as2[0] + rA1 * as2[1], rA0, rA1,
                              rA0 * ad2[0] + rA1 * ad2[1]);
        rec[n1] = make_float4(rB0 * as2[0] + rB1 * as2[1], rB0, rB1,
                              rB0 * ad2[0] + rB1 * ad2[1]);
    }
}

// ---------- conv2 fused with mean-pool (LDS partials, 4-way ILP) ----------
__global__ __launch_bounds__(256) void conv2_pool_kernel(
        const int* __restrict__ rowptr, const int* __restrict__ rowend,
        const int* __restrict__ csr_src, const float4* __restrict__ rec,
        const int* __restrict__ batch,
        float* __restrict__ pooled /*128 sums + 64 counts*/) {
    __shared__ float ls[192];
    int tid = threadIdx.x;
    if (tid < 192) ls[tid] = 0.f;
    __syncthreads();
    int n = blockIdx.x * 256 + tid;
    if (n < NN) {
        float adn = rec[n].w;
        int jb = rowptr[n], je = rowend[n];
        float l0 = 0.f, l1 = 0.f, l2 = 0.f, l3 = 0.f;
        float x0 = 0.f, x1 = 0.f, x2 = 0.f, x3 = 0.f;
        float y0 = 0.f, y1 = 0.f, y2 = 0.f, y3 = 0.f;
        int j = jb;
        for (; j + 3 < je; j += 4) {
            float4 ra = rec[csr_src[j]];
            float4 rb = rec[csr_src[j + 1]];
            float4 rc = rec[csr_src[j + 2]];
            float4 rd = rec[csr_src[j + 3]];
            float pa = __expf(leaky(ra.x + adn));
            float pb = __expf(leaky(rb.x + adn));
            float pc = __expf(leaky(rc.x + adn));
            float pd = __expf(leaky(rd.x + adn));
            l0 += pa; x0 += pa * ra.y; y0 += pa * ra.z;
            l1 += pb; x1 += pb * rb.y; y1 += pb * rb.z;
            l2 += pc; x2 += pc * rc.y; y2 += pc * rc.z;
            l3 += pd; x3 += pd * rd.y; y3 += pd * rd.z;
        }
        for (; j < je; ++j) {
            float4 ra = rec[csr_src[j]];
            float pa = __expf(leaky(ra.x + adn));
            l0 += pa; x0 += pa * ra.y; y0 += pa * ra.z;
        }
        float l = (l0 + l1) + (l2 + l3);
        float xx = (x0 + x1) + (x2 + x3);
        float yy = (y0 + y1) + (y2 + y3);
        float inv = 1.f / (l + 1e-16f);
        int g = batch[n];
        atomicAdd(&ls[g * 2],     xx * inv);
        atomicAdd(&ls[g * 2 + 1], yy * inv);
        atomicAdd(&ls[128 + g],   1.f);
    }
    __syncthreads();
    if (tid < 192) atomicAdd(&pooled[tid], ls[tid]);
}

// ---------- finalize: mean, +b2, log_softmax ----------
__global__ __launch_bounds__(64) void final_kernel(
        const float* __restrict__ pooled, const float* __restrict__ b2,
        float* __restrict__ out) {
    int g = threadIdx.x;
    if (g >= 64) return;
    float c = pooled[128 + g];
    float denom = c > 1.f ? c : 1.f;
    float p0 = pooled[g * 2] / denom + b2[0];
    float p1 = pooled[g * 2 + 1] / denom + b2[1];
    float m = fmaxf(p0, p1);
    float lse = m + logf(expf(p0 - m) + expf(p1 - m));
    out[g * 2] = p0 - lse;
    out[g * 2 + 1] = p1 - lse;
}

extern "C" void kernel_launch(void* const* d_in, const int* in_sizes, int n_in,
                              void* d_out, int out_size, void* d_ws, size_t ws_size,
                              hipStream_t stream) {
    const float* x   = (const float*)d_in[0];
    const int*   ei  = (const int*)d_in[1];     // [2,E] int32
    const int*   bat = (const int*)d_in[2];     // [N]
    const float* W1  = (const float*)d_in[3];
    const float* as1 = (const float*)d_in[4];
    const float* ad1 = (const float*)d_in[5];
    const float* b1  = (const float*)d_in[6];
    const float* W2  = (const float*)d_in[7];
    const float* as2 = (const float*)d_in[8];
    const float* ad2 = (const float*)d_in[9];
    const float* b2  = (const float*)d_in[10];
    float* out = (float*)d_out;

    float* ws = (float*)d_ws;
    // workspace layout (element offsets; 16B-aligned blocks)
    const long off_h1f8   = 0;                          // N*64 bytes = N*16 f
    const long off_wt     = off_h1f8 + (long)NN * 16;   // 8192 halves = 4096 f
    const long off_as1h   = off_wt   + 4096;            // N*8 halves = N*4 f
    const long off_ad1    = off_as1h + (long)NN * 4;    // N*8
    const long off_rec    = off_ad1  + (long)NN * 8;    // N*4 (float4)
    const long off_rowptr = off_rec  + (long)NN * 4;    // N (int)
    const long off_rowend = off_rowptr + NN;            // N (int)
    const long off_gpay   = off_rowend + NN;            // NBUCK*SLAB (uint)
    const long off_csr    = off_gpay + (long)NBUCK * SLAB; // NBUCK*SLAB (int)
    const long off_zero   = off_csr  + (long)NBUCK * SLAB; // ---- zeroed ----
    const long off_bcur   = off_zero;                   // NBUCK*PAD (int)
    const long off_pool   = off_bcur + NBUCK * PAD;     // 192
    const long zero_elems = off_pool + 192 - off_zero;

    hipMemsetAsync(ws + off_zero, 0, zero_elems * sizeof(float), stream);

    convert_w_kernel<<<32, 256, 0, stream>>>(W1, (f16*)(ws + off_wt));
    gemm1_mfma<<<(NN + 63) / 64, 256, 0, stream>>>(
        x, (const f16*)(ws + off_wt), as1, ad1,
        (unsigned char*)(ws + off_h1f8), (__half*)(ws + off_as1h),
        ws + off_ad1);

    bucket_fill<<<NCH2, 256, 0, stream>>>(ei, (int*)(ws + off_bcur),
                                          (unsigned*)(ws + off_gpay));
    fine_csr<<<NBUCK, 256, 0, stream>>>(
        (const unsigned*)(ws + off_gpay), (const int*)(ws + off_bcur),
        (int*)(ws + off_rowptr), (int*)(ws + off_rowend),
        (int*)(ws + off_csr));

    conv1_fused_kernel<<<NN / 8, 256, 0, stream>>>(
        (const int*)(ws + off_rowptr), (const int*)(ws + off_rowend),
        (const int*)(ws + off_csr), (const __half*)(ws + off_as1h),
        ws + off_ad1, (const unsigned char*)(ws + off_h1f8),
        b1, W2, as2, ad2, (float4*)(ws + off_rec));

    conv2_pool_kernel<<<(NN + 255) / 256, 256, 0, stream>>>(
        (const int*)(ws + off_rowptr), (const int*)(ws + off_rowend),
        (const int*)(ws + off_csr), (const float4*)(ws + off_rec),
        bat, ws + off_pool);

    final_kernel<<<1, 64, 0, stream>>>(ws + off_pool, b2, out);
}